// Round 7
// baseline (110.001 us; speedup 1.0000x reference)
//
#include <hip/hip_runtime.h>
#include <float.h>

#define N_NODES 1024
#define F_IN    128
#define K_TOP   9
#define C_OUT   256
#define KDIM    (K_TOP * F_IN)   // 1152

// ---------------------------------------------------------------------------
// Kernel 0: per-feature bitonic argsort, descending. 1024 threads/block,
// one element per thread in registers. Stride<64 stages via __shfl_xor
// (no barrier); stride>=64 via double-buffered LDS (1 barrier each).
// ---------------------------------------------------------------------------
#define CE_SHFL(jj, k) do {                                               \
        const float ov_  = __shfl_xor(v, (jj));                           \
        const int   oix_ = __shfl_xor(ix, (jj));                          \
        const bool amLow_ = ((tid & (jj)) == 0);                          \
        const bool asc_   = ((tid & (k)) == 0);                           \
        const bool keepSmall_ = (amLow_ == asc_);                         \
        const bool less_ = (v < ov_) || (v == ov_ && ix < oix_);          \
        if (keepSmall_ != less_) { v = ov_; ix = oix_; }                  \
    } while (0)

#define CE_LDS(jj, k) do {                                                \
        lv[pbuf][tid] = v; li[pbuf][tid] = ix;                            \
        __syncthreads();                                                  \
        const int p_ = tid ^ (jj);                                        \
        const float ov_  = lv[pbuf][p_];                                  \
        const int   oix_ = li[pbuf][p_];                                  \
        const bool amLow_ = ((tid & (jj)) == 0);                          \
        const bool asc_   = ((tid & (k)) == 0);                           \
        const bool keepSmall_ = (amLow_ == asc_);                         \
        const bool less_ = (v < ov_) || (v == ov_ && ix < oix_);          \
        if (keepSmall_ != less_) { v = ov_; ix = oix_; }                  \
        pbuf ^= 1;                                                        \
    } while (0)

__global__ __launch_bounds__(1024) void sort_fea_kernel(
    const float* __restrict__ fea,   // [N][F]
    float* __restrict__ sval,        // [F][N] descending
    int*   __restrict__ sidx)        // [F][N]
{
    __shared__ float lv[2][N_NODES];
    __shared__ int   li[2][N_NODES];
    const int f   = blockIdx.x;
    const int tid = threadIdx.x;
    int pbuf = 0;

    float v  = fea[(size_t)tid * F_IN + f];
    int   ix = tid;

    #pragma unroll
    for (int k = 2; k <= 64; k <<= 1) {
        #pragma unroll
        for (int jj = k >> 1; jj >= 1; jj >>= 1) CE_SHFL(jj, k);
    }
    #pragma unroll
    for (int k = 128; k <= N_NODES; k <<= 1) {
        #pragma unroll
        for (int jj = k >> 1; jj >= 64; jj >>= 1) CE_LDS(jj, k);
        #pragma unroll
        for (int jj = 32; jj >= 1; jj >>= 1) CE_SHFL(jj, k);
    }

    sval[(size_t)f * N_NODES + (N_NODES - 1 - tid)] = v;
    sidx[(size_t)f * N_NODES + (N_NODES - 1 - tid)] = ix;
}

// ---------------------------------------------------------------------------
// Kernel 1: pruned top-9, software-pipelined. lane = j, wave = f.
// adj in [0,1) => product <= max(fea,0): scanning candidates in
// descending-fea order, once all lanes have s8 >= max(next fea, 0), no
// remaining candidate can insert -> exact early exit.
// ---------------------------------------------------------------------------
#define INSERT9(vv) do {                                                  \
        float v_ = (vv);                                                  \
        if (v_ > s8) {                                                    \
            float t_;                                                     \
            t_ = fminf(s0, v_); s0 = fmaxf(s0, v_); v_ = t_;              \
            t_ = fminf(s1, v_); s1 = fmaxf(s1, v_); v_ = t_;              \
            t_ = fminf(s2, v_); s2 = fmaxf(s2, v_); v_ = t_;              \
            t_ = fminf(s3, v_); s3 = fmaxf(s3, v_); v_ = t_;              \
            t_ = fminf(s4, v_); s4 = fmaxf(s4, v_); v_ = t_;              \
            t_ = fminf(s5, v_); s5 = fmaxf(s5, v_); v_ = t_;              \
            t_ = fminf(s6, v_); s6 = fmaxf(s6, v_); v_ = t_;              \
            t_ = fminf(s7, v_); s7 = fmaxf(s7, v_); v_ = t_;              \
            s8 = fmaxf(s8, v_);                                           \
        }                                                                 \
    } while (0)

__global__ __launch_bounds__(256) void topk_sorted_kernel(
    const float* __restrict__ adj,   // [N][N]
    const float* __restrict__ sval,  // [F][N] descending
    const int*   __restrict__ sidx,  // [F][N]
    float* __restrict__ XT)          // [KDIM][N]
{
    const int lane = threadIdx.x & 63;
    const int wv   = threadIdx.x >> 6;
    const int j = blockIdx.x * 64 + lane;
    const int f = blockIdx.y * 4 + wv;

    const float* __restrict__ sv = sval + (size_t)f * N_NODES;
    const int*   __restrict__ si = sidx + (size_t)f * N_NODES;

    float s0 = -FLT_MAX, s1 = -FLT_MAX, s2 = -FLT_MAX, s3 = -FLT_MAX,
          s4 = -FLT_MAX, s5 = -FLT_MAX, s6 = -FLT_MAX, s7 = -FLT_MAX,
          s8 = -FLT_MAX;

    float4 g0 = *reinterpret_cast<const float4*>(sv);
    float4 g1 = *reinterpret_cast<const float4*>(sv + 4);
    int4   p0 = *reinterpret_cast<const int4*>(si);
    int4   p1 = *reinterpret_cast<const int4*>(si + 4);

    for (int c = 0; c < N_NODES / 8; ++c) {
        const int t0 = c * 8;

        // prefetch next chunk (g0n.x is also the pruning bound)
        const float4 g0n = *reinterpret_cast<const float4*>(sv + t0 + 8);
        const float4 g1n = *reinterpret_cast<const float4*>(sv + t0 + 12);
        const int4   p0n = *reinterpret_cast<const int4*>(si + t0 + 8);
        const int4   p1n = *reinterpret_cast<const int4*>(si + t0 + 12);

        const float a0 = adj[(size_t)p0.x * N_NODES + j];
        const float a1 = adj[(size_t)p0.y * N_NODES + j];
        const float a2 = adj[(size_t)p0.z * N_NODES + j];
        const float a3 = adj[(size_t)p0.w * N_NODES + j];
        const float a4 = adj[(size_t)p1.x * N_NODES + j];
        const float a5 = adj[(size_t)p1.y * N_NODES + j];
        const float a6 = adj[(size_t)p1.z * N_NODES + j];
        const float a7 = adj[(size_t)p1.w * N_NODES + j];

        INSERT9(a0 * g0.x);
        INSERT9(a1 * g0.y);
        INSERT9(a2 * g0.z);
        INSERT9(a3 * g0.w);
        INSERT9(a4 * g1.x);
        INSERT9(a5 * g1.y);
        INSERT9(a6 * g1.z);
        INSERT9(a7 * g1.w);

        if (t0 + 8 >= N_NODES) break;
        const float bound = fmaxf(g0n.x, 0.f);
        if (__all(s8 >= bound)) break;

        g0 = g0n; g1 = g1n; p0 = p0n; p1 = p1n;
    }

    float* __restrict__ xp = XT + (size_t)f * N_NODES + j;
    const size_t kstride = (size_t)F_IN * N_NODES;
    xp[0 * kstride] = s0;
    xp[1 * kstride] = s1;
    xp[2 * kstride] = s2;
    xp[3 * kstride] = s3;
    xp[4 * kstride] = s4;
    xp[5 * kstride] = s5;
    xp[6 * kstride] = s6;
    xp[7 * kstride] = s7;
    xp[8 * kstride] = s8;
}

// ---------------------------------------------------------------------------
// Kernel 2: split-K fp32 GEMM, SPLITK=12 -> 3072 blocks (12/CU queued,
// 8 resident). KCHUNK=96 (3 K-steps of 32). Total staging traffic is
// SPLITK-invariant; this purely buys latency overlap.
// ---------------------------------------------------------------------------
#define BM 32
#define BN 32
#define BK 32
#define SPLITK 12
#define KCHUNK (KDIM / SPLITK)   // 96

__global__ __launch_bounds__(256) void gemm_splitk_kernel(
    const float* __restrict__ XT,   // [KDIM][N_NODES]
    const float* __restrict__ W,    // [KDIM][C_OUT]
    float* __restrict__ part)       // [SPLITK][N_NODES][C_OUT]
{
    __shared__ float As[BK][BM];
    __shared__ float Bs[BK][BN];

    const int m0 = blockIdx.x * BM;
    const int n0 = blockIdx.y * BN;
    const int kb = blockIdx.z * KCHUNK;
    const int tid = threadIdx.x;

    const int tx = tid & 15;
    const int ty = tid >> 4;

    float acc00 = 0.f, acc01 = 0.f, acc10 = 0.f, acc11 = 0.f;

    const int le  = tid * 4;
    const int lkk = le >> 5;
    const int lmm = le & 31;

    #pragma unroll
    for (int ks = 0; ks < KCHUNK / BK; ++ks) {
        const int k0 = kb + ks * BK;
        const float4 av = *reinterpret_cast<const float4*>(
            &XT[(size_t)(k0 + lkk) * N_NODES + m0 + lmm]);
        const float4 bv = *reinterpret_cast<const float4*>(
            &W[(size_t)(k0 + lkk) * C_OUT + n0 + lmm]);
        *reinterpret_cast<float4*>(&As[lkk][lmm]) = av;
        *reinterpret_cast<float4*>(&Bs[lkk][lmm]) = bv;
        __syncthreads();

        #pragma unroll
        for (int kk = 0; kk < BK; ++kk) {
            const float2 a = *reinterpret_cast<const float2*>(&As[kk][ty * 2]);
            const float2 b = *reinterpret_cast<const float2*>(&Bs[kk][tx * 2]);
            acc00 = fmaf(a.x, b.x, acc00);
            acc01 = fmaf(a.x, b.y, acc01);
            acc10 = fmaf(a.y, b.x, acc10);
            acc11 = fmaf(a.y, b.y, acc11);
        }
        __syncthreads();
    }

    const int m = m0 + ty * 2;
    const int n = n0 + tx * 2;
    float* __restrict__ pp = part + (size_t)blockIdx.z * N_NODES * C_OUT;
    pp[(size_t)m * C_OUT + n]           = acc00;
    pp[(size_t)m * C_OUT + n + 1]       = acc01;
    pp[(size_t)(m + 1) * C_OUT + n]     = acc10;
    pp[(size_t)(m + 1) * C_OUT + n + 1] = acc11;
}

// ---------------------------------------------------------------------------
// Kernel 3: reduce split-K partials + bias + ReLU. 1024 blocks x 64 thr
// (4 blocks/CU) so the 12 independent loads overlap across many waves.
// ---------------------------------------------------------------------------
__global__ __launch_bounds__(64) void reduce_kernel(
    const float* __restrict__ part,  // [SPLITK][N_NODES][C_OUT]
    const float* __restrict__ bias,  // [C_OUT]
    float* __restrict__ out)         // [N_NODES][C_OUT]
{
    const int idx = (blockIdx.x * 64 + threadIdx.x) * 4;
    const int n = idx & (C_OUT - 1);
    float4 s = *reinterpret_cast<const float4*>(part + idx);
    #pragma unroll
    for (int sp = 1; sp < SPLITK; ++sp) {
        const float4 p = *reinterpret_cast<const float4*>(
            part + (size_t)sp * N_NODES * C_OUT + idx);
        s.x += p.x; s.y += p.y; s.z += p.z; s.w += p.w;
    }
    const float4 bb = *reinterpret_cast<const float4*>(bias + n);
    float4 r;
    r.x = fmaxf(s.x + bb.x, 0.f);
    r.y = fmaxf(s.y + bb.y, 0.f);
    r.z = fmaxf(s.z + bb.z, 0.f);
    r.w = fmaxf(s.w + bb.w, 0.f);
    *reinterpret_cast<float4*>(out + idx) = r;
}

extern "C" void kernel_launch(void* const* d_in, const int* in_sizes, int n_in,
                              void* d_out, int out_size, void* d_ws, size_t ws_size,
                              hipStream_t stream) {
    const float* adj  = (const float*)d_in[0];  // 1024*1024
    const float* fea  = (const float*)d_in[1];  // 1024*128
    const float* W    = (const float*)d_in[2];  // 1152*256 (K,F,OUT row-major)
    const float* bias = (const float*)d_in[3];  // 256
    float* out = (float*)d_out;                 // 1024*256

    // workspace layout (16B-aligned):
    float* XT   = (float*)d_ws;                             // 1152*1024 f
    float* sval = XT + (size_t)KDIM * N_NODES;              // 128*1024 f
    int*   sidx = (int*)(sval + (size_t)F_IN * N_NODES);    // 128*1024 i
    float* part = (float*)(sidx + (size_t)F_IN * N_NODES);  // 12*1024*256 f

    sort_fea_kernel<<<F_IN, 1024, 0, stream>>>(fea, sval, sidx);

    dim3 grid1(N_NODES / 64, F_IN / 4);                 // 512 blocks
    topk_sorted_kernel<<<grid1, 256, 0, stream>>>(adj, sval, sidx, XT);

    dim3 grid2(N_NODES / BM, C_OUT / BN, SPLITK);       // 32 x 8 x 12 = 3072 blocks
    gemm_splitk_kernel<<<grid2, 256, 0, stream>>>(XT, W, part);

    reduce_kernel<<<N_NODES * C_OUT / (64 * 4), 64, 0, stream>>>(part, bias, out);
}

// Round 8
// 106.322 us; speedup vs baseline: 1.0346x; 1.0346x over previous
//
#include <hip/hip_runtime.h>
#include <float.h>

#define N_NODES 1024
#define F_IN    128
#define K_TOP   9
#define C_OUT   256
#define KDIM    (K_TOP * F_IN)   // 1152

// ---------------------------------------------------------------------------
// Kernel 0: per-feature bitonic argsort, descending. 1024 threads/block,
// one element per thread in registers. Stride<64 stages via __shfl_xor
// (no barrier); stride>=64 via double-buffered LDS (1 barrier each).
// ---------------------------------------------------------------------------
#define CE_SHFL(jj, k) do {                                               \
        const float ov_  = __shfl_xor(v, (jj));                           \
        const int   oix_ = __shfl_xor(ix, (jj));                          \
        const bool amLow_ = ((tid & (jj)) == 0);                          \
        const bool asc_   = ((tid & (k)) == 0);                           \
        const bool keepSmall_ = (amLow_ == asc_);                         \
        const bool less_ = (v < ov_) || (v == ov_ && ix < oix_);          \
        if (keepSmall_ != less_) { v = ov_; ix = oix_; }                  \
    } while (0)

#define CE_LDS(jj, k) do {                                                \
        lv[pbuf][tid] = v; li[pbuf][tid] = ix;                            \
        __syncthreads();                                                  \
        const int p_ = tid ^ (jj);                                        \
        const float ov_  = lv[pbuf][p_];                                  \
        const int   oix_ = li[pbuf][p_];                                  \
        const bool amLow_ = ((tid & (jj)) == 0);                          \
        const bool asc_   = ((tid & (k)) == 0);                           \
        const bool keepSmall_ = (amLow_ == asc_);                         \
        const bool less_ = (v < ov_) || (v == ov_ && ix < oix_);          \
        if (keepSmall_ != less_) { v = ov_; ix = oix_; }                  \
        pbuf ^= 1;                                                        \
    } while (0)

__global__ __launch_bounds__(1024) void sort_fea_kernel(
    const float* __restrict__ fea,   // [N][F]
    float* __restrict__ sval,        // [F][N] descending
    int*   __restrict__ sidx)        // [F][N]
{
    __shared__ float lv[2][N_NODES];
    __shared__ int   li[2][N_NODES];
    const int f   = blockIdx.x;
    const int tid = threadIdx.x;
    int pbuf = 0;

    float v  = fea[(size_t)tid * F_IN + f];
    int   ix = tid;

    #pragma unroll
    for (int k = 2; k <= 64; k <<= 1) {
        #pragma unroll
        for (int jj = k >> 1; jj >= 1; jj >>= 1) CE_SHFL(jj, k);
    }
    #pragma unroll
    for (int k = 128; k <= N_NODES; k <<= 1) {
        #pragma unroll
        for (int jj = k >> 1; jj >= 64; jj >>= 1) CE_LDS(jj, k);
        #pragma unroll
        for (int jj = 32; jj >= 1; jj >>= 1) CE_SHFL(jj, k);
    }

    sval[(size_t)f * N_NODES + (N_NODES - 1 - tid)] = v;
    sidx[(size_t)f * N_NODES + (N_NODES - 1 - tid)] = ix;
}

// ---------------------------------------------------------------------------
// Kernel 1: pruned top-9, software-pipelined. SINGLE-WAVE blocks (64 thr):
// each wave's early-exit frees its CU slot independently (block lifetime =
// its own scan depth, not max over 4 waves). lane = j, block.y = f.
// adj in [0,1) => product <= max(fea,0): scanning candidates in
// descending-fea order, once all lanes have s8 >= max(next fea, 0), no
// remaining candidate can insert -> exact early exit.
// ---------------------------------------------------------------------------
#define INSERT9(vv) do {                                                  \
        float v_ = (vv);                                                  \
        if (v_ > s8) {                                                    \
            float t_;                                                     \
            t_ = fminf(s0, v_); s0 = fmaxf(s0, v_); v_ = t_;              \
            t_ = fminf(s1, v_); s1 = fmaxf(s1, v_); v_ = t_;              \
            t_ = fminf(s2, v_); s2 = fmaxf(s2, v_); v_ = t_;              \
            t_ = fminf(s3, v_); s3 = fmaxf(s3, v_); v_ = t_;              \
            t_ = fminf(s4, v_); s4 = fmaxf(s4, v_); v_ = t_;              \
            t_ = fminf(s5, v_); s5 = fmaxf(s5, v_); v_ = t_;              \
            t_ = fminf(s6, v_); s6 = fmaxf(s6, v_); v_ = t_;              \
            t_ = fminf(s7, v_); s7 = fmaxf(s7, v_); v_ = t_;              \
            s8 = fmaxf(s8, v_);                                           \
        }                                                                 \
    } while (0)

__global__ __launch_bounds__(64) void topk_sorted_kernel(
    const float* __restrict__ adj,   // [N][N]
    const float* __restrict__ sval,  // [F][N] descending
    const int*   __restrict__ sidx,  // [F][N]
    float* __restrict__ XT)          // [KDIM][N]
{
    const int lane = threadIdx.x;
    const int j = blockIdx.x * 64 + lane;
    const int f = blockIdx.y;

    const float* __restrict__ sv = sval + (size_t)f * N_NODES;
    const int*   __restrict__ si = sidx + (size_t)f * N_NODES;

    float s0 = -FLT_MAX, s1 = -FLT_MAX, s2 = -FLT_MAX, s3 = -FLT_MAX,
          s4 = -FLT_MAX, s5 = -FLT_MAX, s6 = -FLT_MAX, s7 = -FLT_MAX,
          s8 = -FLT_MAX;

    float4 g0 = *reinterpret_cast<const float4*>(sv);
    float4 g1 = *reinterpret_cast<const float4*>(sv + 4);
    int4   p0 = *reinterpret_cast<const int4*>(si);
    int4   p1 = *reinterpret_cast<const int4*>(si + 4);

    for (int c = 0; c < N_NODES / 8; ++c) {
        const int t0 = c * 8;

        // prefetch next chunk (g0n.x is also the pruning bound)
        const float4 g0n = *reinterpret_cast<const float4*>(sv + t0 + 8);
        const float4 g1n = *reinterpret_cast<const float4*>(sv + t0 + 12);
        const int4   p0n = *reinterpret_cast<const int4*>(si + t0 + 8);
        const int4   p1n = *reinterpret_cast<const int4*>(si + t0 + 12);

        const float a0 = adj[(size_t)p0.x * N_NODES + j];
        const float a1 = adj[(size_t)p0.y * N_NODES + j];
        const float a2 = adj[(size_t)p0.z * N_NODES + j];
        const float a3 = adj[(size_t)p0.w * N_NODES + j];
        const float a4 = adj[(size_t)p1.x * N_NODES + j];
        const float a5 = adj[(size_t)p1.y * N_NODES + j];
        const float a6 = adj[(size_t)p1.z * N_NODES + j];
        const float a7 = adj[(size_t)p1.w * N_NODES + j];

        INSERT9(a0 * g0.x);
        INSERT9(a1 * g0.y);
        INSERT9(a2 * g0.z);
        INSERT9(a3 * g0.w);
        INSERT9(a4 * g1.x);
        INSERT9(a5 * g1.y);
        INSERT9(a6 * g1.z);
        INSERT9(a7 * g1.w);

        if (t0 + 8 >= N_NODES) break;
        const float bound = fmaxf(g0n.x, 0.f);
        if (__all(s8 >= bound)) break;

        g0 = g0n; g1 = g1n; p0 = p0n; p1 = p1n;
    }

    float* __restrict__ xp = XT + (size_t)f * N_NODES + j;
    const size_t kstride = (size_t)F_IN * N_NODES;
    xp[0 * kstride] = s0;
    xp[1 * kstride] = s1;
    xp[2 * kstride] = s2;
    xp[3 * kstride] = s3;
    xp[4 * kstride] = s4;
    xp[5 * kstride] = s5;
    xp[6 * kstride] = s6;
    xp[7 * kstride] = s7;
    xp[8 * kstride] = s8;
}

// ---------------------------------------------------------------------------
// Kernel 2: split-K fp32 GEMM, SPLITK=6 -> 1536 blocks (6/CU, 24 waves/CU).
// 32x32 tile, 2x2 micro-tile, KCHUNK=192 (6 K-steps of 32). R6-measured best.
// ---------------------------------------------------------------------------
#define BM 32
#define BN 32
#define BK 32
#define SPLITK 6
#define KCHUNK (KDIM / SPLITK)   // 192

__global__ __launch_bounds__(256) void gemm_splitk_kernel(
    const float* __restrict__ XT,   // [KDIM][N_NODES]
    const float* __restrict__ W,    // [KDIM][C_OUT]
    float* __restrict__ part)       // [SPLITK][N_NODES][C_OUT]
{
    __shared__ float As[BK][BM];
    __shared__ float Bs[BK][BN];

    const int m0 = blockIdx.x * BM;
    const int n0 = blockIdx.y * BN;
    const int kb = blockIdx.z * KCHUNK;
    const int tid = threadIdx.x;

    const int tx = tid & 15;
    const int ty = tid >> 4;

    float acc00 = 0.f, acc01 = 0.f, acc10 = 0.f, acc11 = 0.f;

    const int le  = tid * 4;
    const int lkk = le >> 5;
    const int lmm = le & 31;

    for (int k0 = kb; k0 < kb + KCHUNK; k0 += BK) {
        const float4 av = *reinterpret_cast<const float4*>(
            &XT[(size_t)(k0 + lkk) * N_NODES + m0 + lmm]);
        const float4 bv = *reinterpret_cast<const float4*>(
            &W[(size_t)(k0 + lkk) * C_OUT + n0 + lmm]);
        *reinterpret_cast<float4*>(&As[lkk][lmm]) = av;
        *reinterpret_cast<float4*>(&Bs[lkk][lmm]) = bv;
        __syncthreads();

        #pragma unroll
        for (int kk = 0; kk < BK; ++kk) {
            const float2 a = *reinterpret_cast<const float2*>(&As[kk][ty * 2]);
            const float2 b = *reinterpret_cast<const float2*>(&Bs[kk][tx * 2]);
            acc00 = fmaf(a.x, b.x, acc00);
            acc01 = fmaf(a.x, b.y, acc01);
            acc10 = fmaf(a.y, b.x, acc10);
            acc11 = fmaf(a.y, b.y, acc11);
        }
        __syncthreads();
    }

    const int m = m0 + ty * 2;
    const int n = n0 + tx * 2;
    float* __restrict__ pp = part + (size_t)blockIdx.z * N_NODES * C_OUT;
    pp[(size_t)m * C_OUT + n]           = acc00;
    pp[(size_t)m * C_OUT + n + 1]       = acc01;
    pp[(size_t)(m + 1) * C_OUT + n]     = acc10;
    pp[(size_t)(m + 1) * C_OUT + n + 1] = acc11;
}

// ---------------------------------------------------------------------------
// Kernel 3: reduce split-K partials + bias + ReLU. float4 per thread.
// ---------------------------------------------------------------------------
__global__ __launch_bounds__(256) void reduce_kernel(
    const float* __restrict__ part,  // [SPLITK][N_NODES][C_OUT]
    const float* __restrict__ bias,  // [C_OUT]
    float* __restrict__ out)         // [N_NODES][C_OUT]
{
    const int idx = (blockIdx.x * 256 + threadIdx.x) * 4;
    const int n = idx & (C_OUT - 1);
    float4 s = *reinterpret_cast<const float4*>(part + idx);
    #pragma unroll
    for (int sp = 1; sp < SPLITK; ++sp) {
        const float4 p = *reinterpret_cast<const float4*>(
            part + (size_t)sp * N_NODES * C_OUT + idx);
        s.x += p.x; s.y += p.y; s.z += p.z; s.w += p.w;
    }
    const float4 bb = *reinterpret_cast<const float4*>(bias + n);
    float4 r;
    r.x = fmaxf(s.x + bb.x, 0.f);
    r.y = fmaxf(s.y + bb.y, 0.f);
    r.z = fmaxf(s.z + bb.z, 0.f);
    r.w = fmaxf(s.w + bb.w, 0.f);
    *reinterpret_cast<float4*>(out + idx) = r;
}

extern "C" void kernel_launch(void* const* d_in, const int* in_sizes, int n_in,
                              void* d_out, int out_size, void* d_ws, size_t ws_size,
                              hipStream_t stream) {
    const float* adj  = (const float*)d_in[0];  // 1024*1024
    const float* fea  = (const float*)d_in[1];  // 1024*128
    const float* W    = (const float*)d_in[2];  // 1152*256 (K,F,OUT row-major)
    const float* bias = (const float*)d_in[3];  // 256
    float* out = (float*)d_out;                 // 1024*256

    // workspace layout (16B-aligned):
    float* XT   = (float*)d_ws;                             // 1152*1024 f
    float* sval = XT + (size_t)KDIM * N_NODES;              // 128*1024 f
    int*   sidx = (int*)(sval + (size_t)F_IN * N_NODES);    // 128*1024 i
    float* part = (float*)(sidx + (size_t)F_IN * N_NODES);  // 6*1024*256 f

    sort_fea_kernel<<<F_IN, 1024, 0, stream>>>(fea, sval, sidx);

    dim3 grid1(N_NODES / 64, F_IN);                     // 16 x 128 = 2048 single-wave blocks
    topk_sorted_kernel<<<grid1, 64, 0, stream>>>(adj, sval, sidx, XT);

    dim3 grid2(N_NODES / BM, C_OUT / BN, SPLITK);       // 32 x 8 x 6 = 1536 blocks
    gemm_splitk_kernel<<<grid2, 256, 0, stream>>>(XT, W, part);

    reduce_kernel<<<N_NODES * C_OUT / (256 * 4), 256, 0, stream>>>(part, bias, out);
}